// Round 8
// baseline (115.134 us; speedup 1.0000x reference)
//
#include <hip/hip_runtime.h>

#define DETN 128
#define NPIX (DETN * DETN)        // 16384 rays per projection
#define VDIM 128
#define NVOX (VDIM * VDIM * VDIM) // 2097152
#define NWORDS (NVOX / 32)        // 65536 words = 256 KiB per bit-volume
#define NSAMP 512
#define SPLITK 8                  // 2048 blocks -> 8 blocks/CU for latency hiding

// ---------------------------------------------------------------------------
// Backprojection (R2-verified math, absmax 0.0). Dual-packed bitmaps:
//   frontal (view 0): z-packed  word = ix<<9 | iy<<2 | iz>>5, bit iz&31
//   lateral (view 1): x-packed  word = iz<<9 | iy<<2 | ix>>5, bit ix&31
// Run-merged bits -> one fire-and-forget atomicOr per ~13 samples.
// grid = (NPIX/256, 2B, SPLITK). Also zeroes *out (loss is a later dispatch).
// ---------------------------------------------------------------------------
__global__ __launch_bounds__(256) void bp_kernel(
    const float* __restrict__ predF, const float* __restrict__ predL,
    const float* __restrict__ srcF,  const float* __restrict__ srcL,
    const float* __restrict__ tgtF,  const float* __restrict__ tgtL,
    const float* __restrict__ Ainv,  const float* __restrict__ tinv,
    unsigned int* __restrict__ flags, float* __restrict__ out)
{
    if (blockIdx.x == 0 && blockIdx.y == 0 && blockIdx.z == 0 &&
        threadIdx.x == 0) {
        *out = 0.0f;    // replaces a separate memset dispatch
    }

    const int p     = blockIdx.y;
    const int view  = p & 1;
    const int batch = p >> 1;
    const int ray   = blockIdx.x * blockDim.x + threadIdx.x;

    const float* mask = (view ? predL : predF) + batch * NPIX;
    if (!(mask[ray] > 0.5f)) return;   // inactive ray

    const float* src = view ? srcL : srcF;
    const float* tgt = (view ? tgtL : tgtF) + ray * 3;

    const float sx = src[0], sy = src[1], sz = src[2];
    float dx = tgt[0] - sx, dy = tgt[1] - sy, dz = tgt[2] - sz;
    const float len = sqrtf(dx * dx + dy * dy + dz * dz);
    const float inv = 1.0f / (len + 1e-8f);
    dx *= inv; dy *= inv; dz *= inv;

    // voxel coords affine in t:  q(t) = qc + qd * t
    const float a00 = Ainv[0], a01 = Ainv[1], a02 = Ainv[2];
    const float a10 = Ainv[3], a11 = Ainv[4], a12 = Ainv[5];
    const float a20 = Ainv[6], a21 = Ainv[7], a22 = Ainv[8];
    const float qcx = a00 * sx + a01 * sy + a02 * sz + tinv[0];
    const float qcy = a10 * sx + a11 * sy + a12 * sz + tinv[1];
    const float qcz = a20 * sx + a21 * sy + a22 * sz + tinv[2];
    const float qdx = a00 * dx + a01 * dy + a02 * dz;
    const float qdy = a10 * dx + a11 * dy + a12 * dz;
    const float qdz = a20 * dx + a21 * dy + a22 * dz;

    const float tmax = len * 2.5f;
    const float dt   = tmax * (1.0f / 511.0f);   // t_k = k * dt

    // slab intersection (with margin) to skip out-of-bounds samples
    float tlo = 0.0f, thi = tmax;
    {
        const float c[3] = {qcx, qcy, qcz};
        const float d[3] = {qdx, qdy, qdz};
        #pragma unroll
        for (int j = 0; j < 3; ++j) {
            if (fabsf(d[j]) < 1e-8f) {
                if (c[j] < -0.6f || c[j] > 127.6f) thi = -1.0f;  // empty
            } else {
                const float ta = (-0.6f  - c[j]) / d[j];
                const float tb = (127.6f - c[j]) / d[j];
                tlo = fmaxf(tlo, fminf(ta, tb));
                thi = fminf(thi, fmaxf(ta, tb));
            }
        }
    }
    if (tlo > thi) return;
    const int klo = max(0, (int)ceilf(tlo / dt));
    const int khi = min(NSAMP - 1, (int)floorf(thi / dt));

    // this block-z's k-segment
    const int n   = khi - klo + 1;
    const int per = (n + SPLITK - 1) / SPLITK;
    const int k0  = klo + (int)blockIdx.z * per;
    const int k1  = min(khi, k0 + per - 1);
    if (k0 > khi) return;

    unsigned int* __restrict__ vol = flags + (size_t)p * NWORDS;
    int      curw = -1;
    unsigned bits = 0;
    for (int k = k0; k <= k1; ++k) {
        const float t  = (float)k * dt;
        const float qx = fmaf(qdx, t, qcx);
        const float qy = fmaf(qdy, t, qcy);
        const float qz = fmaf(qdz, t, qcz);
        const int ix = (int)rintf(qx);   // ties-to-even, matches jnp.round
        const int iy = (int)rintf(qy);
        const int iz = (int)rintf(qz);
        if ((unsigned)ix < (unsigned)VDIM && (unsigned)iy < (unsigned)VDIM &&
            (unsigned)iz < (unsigned)VDIM) {
            const int maj = view ? iz : ix;   // slow axis
            const int pk  = view ? ix : iz;   // packed (fast) axis
            const int w   = (maj << 9) | (iy << 2) | (pk >> 5);
            const unsigned bit = 1u << (pk & 31);
            if (w == curw) {
                bits |= bit;
            } else {
                if (curw >= 0) atomicOr(&vol[curw], bits);
                curw = w; bits = bit;
            }
        }
    }
    if (curw >= 0) atomicOr(&vol[curw], bits);
}

// ---------------------------------------------------------------------------
// Loss v3: LDS-staged transpose, one batch per block (gridDim.y = B).
// Block covers x in [32*X0, 32*X0+32), y in {y0,y0+1}, Z in 0..3 -> 256 output
// words, 1 word (32 voxels)/thread. Lateral words staged once into LDS (every
// bit used); frontal words staged too. k = bitF+bitL in {0,1,2};
// BCE/voxel = -log(1-sigmoid(k)) - g*k.
// ---------------------------------------------------------------------------
__global__ __launch_bounds__(256) void loss_kernel(
    const unsigned int* __restrict__ flags,
    const float* __restrict__ gt,
    float* __restrict__ out, float scale)
{
    __shared__ unsigned latw[2][128];     // [yi][z]
    __shared__ unsigned fst[256];         // [xi<<3 | yi<<2 | Zi]
    __shared__ float    smem[4];

    const int X0 = blockIdx.x & 3;
    const int y0 = (blockIdx.x >> 2) << 1;
    const int b  = blockIdx.y;
    const int tid = threadIdx.x;

    // ---- stage: 256 words each of lateral and frontal for this batch ----
    {   // lateral: word (z<<9) | ((y0+yi)<<2) | X0
        const int yi = tid >> 7;
        const int z  = tid & 127;
        latw[yi][z] =
            flags[(size_t)(2 * b + 1) * NWORDS + (z << 9) + ((y0 + yi) << 2) + X0];
    }
    {   // frontal: word ((32X0+xi)<<9) | ((y0+yi)<<2) | Zi
        const int xi = tid >> 3;
        const int yi = (tid >> 2) & 1;
        const int Zi = tid & 3;
        fst[tid] =
            flags[(size_t)(2 * b) * NWORDS + ((32 * X0 + xi) << 9) +
                  ((y0 + yi) << 2) + Zi];
    }
    __syncthreads();

    // ---- compute: this thread's z-packed output word ----
    const int xi = tid & 31;
    const int yi = (tid >> 5) & 1;
    const int Zi = tid >> 6;
    const int w  = ((32 * X0 + xi) << 9) | ((y0 + yi) << 2) | Zi;

    const float4* __restrict__ g4 = (const float4*)(gt + (size_t)w * 32);
    float g[32];
    #pragma unroll
    for (int q = 0; q < 8; ++q) {
        const float4 v = g4[q];
        g[4 * q + 0] = v.x; g[4 * q + 1] = v.y;
        g[4 * q + 2] = v.z; g[4 * q + 3] = v.w;
    }

    float acc = 0.0f;
    {
        const unsigned F = fst[(xi << 3) | (yi << 2) | Zi];
        unsigned L = 0;
        #pragma unroll
        for (int zz = 0; zz < 32; ++zz) {
            L |= ((latw[yi][(Zi << 5) + zz] >> xi) & 1u) << zz;
        }
        const int n2 = __popc(F & L);
        const int n1 = __popc(F | L) - n2;
        const int n0 = 32 - n1 - n2;
        acc += 0.6931471806f * (float)n0 + 1.3132616875f * (float)n1 +
               2.1269280110f * (float)n2;
        float s = 0.0f;
        #pragma unroll
        for (int i = 0; i < 32; ++i) {
            s += g[i] * (float)(((F >> i) & 1u) + ((L >> i) & 1u));
        }
        acc -= s;
    }

    // wave reduce (64 lanes) then block reduce, one atomicAdd per block
    #pragma unroll
    for (int off = 32; off > 0; off >>= 1) acc += __shfl_down(acc, off);

    const int wid  = tid >> 6;
    const int lane = tid & 63;
    if (lane == 0) smem[wid] = acc;
    __syncthreads();
    if (tid == 0) {
        const float tot = smem[0] + smem[1] + smem[2] + smem[3];
        atomicAdd(out, tot * scale);
    }
}

extern "C" void kernel_launch(void* const* d_in, const int* in_sizes, int n_in,
                              void* d_out, int out_size, void* d_ws, size_t ws_size,
                              hipStream_t stream) {
    const float* predF = (const float*)d_in[0];
    const float* predL = (const float*)d_in[1];
    const float* srcF  = (const float*)d_in[2];
    const float* tgtF  = (const float*)d_in[3];
    const float* srcL  = (const float*)d_in[4];
    const float* tgtL  = (const float*)d_in[5];
    const float* gt    = (const float*)d_in[6];
    const float* Ainv  = (const float*)d_in[7];
    const float* tinv  = (const float*)d_in[8];

    const int B = in_sizes[0] / NPIX;               // = 2
    unsigned int* flags = (unsigned int*)d_ws;      // 2B bit-volumes, 256 KiB each
    float* outp = (float*)d_out;

    hipMemsetAsync(flags, 0, (size_t)(2 * B) * NWORDS * sizeof(unsigned int), stream);

    dim3 gridBp(NPIX / 256, 2 * B, SPLITK);
    bp_kernel<<<gridBp, 256, 0, stream>>>(predF, predL, srcF, srcL,
                                          tgtF, tgtL, Ainv, tinv, flags, outp);

    const float scale = 1.0f / ((float)NVOX * (float)B);
    dim3 gridLoss(256, B);
    loss_kernel<<<gridLoss, 256, 0, stream>>>(flags, gt, outp, scale);
}

// Round 9
// 111.983 us; speedup vs baseline: 1.0281x; 1.0281x over previous
//
#include <hip/hip_runtime.h>

#define DETN 128
#define NPIX (DETN * DETN)        // 16384 rays per projection
#define VDIM 128
#define NVOX (VDIM * VDIM * VDIM) // 2097152
#define NWORDS (NVOX / 32)        // 65536 words = 256 KiB per bit-volume
#define NSAMP 512
#define SPLITK 4                  // R8 probe: 8 regressed (per-ray setup dominates)

// ---------------------------------------------------------------------------
// Backprojection (R2-verified math, absmax 0.0). Dual-packed bitmaps:
//   frontal (view 0): z-packed  word = ix<<9 | iy<<2 | iz>>5, bit iz&31
//   lateral (view 1): x-packed  word = iz<<9 | iy<<2 | ix>>5, bit ix&31
// Run-merged bits -> one fire-and-forget atomicOr per ~13 samples.
// grid = (NPIX/256, 2B, SPLITK). Also zeroes *out (loss is a later dispatch).
// ---------------------------------------------------------------------------
__global__ __launch_bounds__(256) void bp_kernel(
    const float* __restrict__ predF, const float* __restrict__ predL,
    const float* __restrict__ srcF,  const float* __restrict__ srcL,
    const float* __restrict__ tgtF,  const float* __restrict__ tgtL,
    const float* __restrict__ Ainv,  const float* __restrict__ tinv,
    unsigned int* __restrict__ flags, float* __restrict__ out)
{
    if (blockIdx.x == 0 && blockIdx.y == 0 && blockIdx.z == 0 &&
        threadIdx.x == 0) {
        *out = 0.0f;    // replaces a separate memset dispatch
    }

    const int p     = blockIdx.y;
    const int view  = p & 1;
    const int batch = p >> 1;
    const int ray   = blockIdx.x * blockDim.x + threadIdx.x;

    const float* mask = (view ? predL : predF) + batch * NPIX;
    if (!(mask[ray] > 0.5f)) return;   // inactive ray

    const float* src = view ? srcL : srcF;
    const float* tgt = (view ? tgtL : tgtF) + ray * 3;

    const float sx = src[0], sy = src[1], sz = src[2];
    float dx = tgt[0] - sx, dy = tgt[1] - sy, dz = tgt[2] - sz;
    const float len = sqrtf(dx * dx + dy * dy + dz * dz);
    const float inv = 1.0f / (len + 1e-8f);
    dx *= inv; dy *= inv; dz *= inv;

    // voxel coords affine in t:  q(t) = qc + qd * t
    const float a00 = Ainv[0], a01 = Ainv[1], a02 = Ainv[2];
    const float a10 = Ainv[3], a11 = Ainv[4], a12 = Ainv[5];
    const float a20 = Ainv[6], a21 = Ainv[7], a22 = Ainv[8];
    const float qcx = a00 * sx + a01 * sy + a02 * sz + tinv[0];
    const float qcy = a10 * sx + a11 * sy + a12 * sz + tinv[1];
    const float qcz = a20 * sx + a21 * sy + a22 * sz + tinv[2];
    const float qdx = a00 * dx + a01 * dy + a02 * dz;
    const float qdy = a10 * dx + a11 * dy + a12 * dz;
    const float qdz = a20 * dx + a21 * dy + a22 * dz;

    const float tmax = len * 2.5f;
    const float dt   = tmax * (1.0f / 511.0f);   // t_k = k * dt

    // slab intersection (with margin) to skip out-of-bounds samples
    float tlo = 0.0f, thi = tmax;
    {
        const float c[3] = {qcx, qcy, qcz};
        const float d[3] = {qdx, qdy, qdz};
        #pragma unroll
        for (int j = 0; j < 3; ++j) {
            if (fabsf(d[j]) < 1e-8f) {
                if (c[j] < -0.6f || c[j] > 127.6f) thi = -1.0f;  // empty
            } else {
                const float ta = (-0.6f  - c[j]) / d[j];
                const float tb = (127.6f - c[j]) / d[j];
                tlo = fmaxf(tlo, fminf(ta, tb));
                thi = fminf(thi, fmaxf(ta, tb));
            }
        }
    }
    if (tlo > thi) return;
    const int klo = max(0, (int)ceilf(tlo / dt));
    const int khi = min(NSAMP - 1, (int)floorf(thi / dt));

    // this block-z's k-segment
    const int n   = khi - klo + 1;
    const int per = (n + SPLITK - 1) / SPLITK;
    const int k0  = klo + (int)blockIdx.z * per;
    const int k1  = min(khi, k0 + per - 1);
    if (k0 > khi) return;

    unsigned int* __restrict__ vol = flags + (size_t)p * NWORDS;
    int      curw = -1;
    unsigned bits = 0;
    for (int k = k0; k <= k1; ++k) {
        const float t  = (float)k * dt;
        const float qx = fmaf(qdx, t, qcx);
        const float qy = fmaf(qdy, t, qcy);
        const float qz = fmaf(qdz, t, qcz);
        const int ix = (int)rintf(qx);   // ties-to-even, matches jnp.round
        const int iy = (int)rintf(qy);
        const int iz = (int)rintf(qz);
        if ((unsigned)ix < (unsigned)VDIM && (unsigned)iy < (unsigned)VDIM &&
            (unsigned)iz < (unsigned)VDIM) {
            const int maj = view ? iz : ix;   // slow axis
            const int pk  = view ? ix : iz;   // packed (fast) axis
            const int w   = (maj << 9) | (iy << 2) | (pk >> 5);
            const unsigned bit = 1u << (pk & 31);
            if (w == curw) {
                bits |= bit;
            } else {
                if (curw >= 0) atomicOr(&vol[curw], bits);
                curw = w; bits = bit;
            }
        }
    }
    if (curw >= 0) atomicOr(&vol[curw], bits);
}

// ---------------------------------------------------------------------------
// Loss v2 (R7-verified): LDS-staged transpose. Block covers x in
// [32*X0, 32*X0+32), y in {y0,y0+1}, Z in 0..3 -> 256 output words,
// 1 word (32 voxels)/thread, both batches per block. Lateral words staged
// once into LDS (every bit used); frontal words staged too.
// k = bitF+bitL in {0,1,2}; BCE/voxel = -log(1-sigmoid(k)) - g*k.
// ---------------------------------------------------------------------------
__global__ __launch_bounds__(256) void loss_kernel(
    const unsigned int* __restrict__ flags,
    const float* __restrict__ gt,
    float* __restrict__ out, float scale)
{
    __shared__ unsigned latw[2][2][128];  // [batch][yi][z]
    __shared__ unsigned fst[2][256];      // [batch][xi<<3 | yi<<2 | Zi]
    __shared__ float    smem[4];

    const int X0 = blockIdx.x & 3;
    const int y0 = (blockIdx.x >> 2) << 1;
    const int tid = threadIdx.x;

    // ---- stage: 2 batches x 256 words each of lateral and frontal ----
    #pragma unroll
    for (int b = 0; b < 2; ++b) {
        {   // lateral: word (z<<9) | ((y0+yi)<<2) | X0
            const int yi = tid >> 7;
            const int z  = tid & 127;
            latw[b][yi][z] =
                flags[(size_t)(2 * b + 1) * NWORDS + (z << 9) + ((y0 + yi) << 2) + X0];
        }
        {   // frontal: word ((32X0+xi)<<9) | ((y0+yi)<<2) | Zi
            const int xi = tid >> 3;
            const int yi = (tid >> 2) & 1;
            const int Zi = tid & 3;
            fst[b][tid] =
                flags[(size_t)(2 * b) * NWORDS + ((32 * X0 + xi) << 9) +
                      ((y0 + yi) << 2) + Zi];
        }
    }
    __syncthreads();

    // ---- compute: this thread's z-packed output word ----
    const int xi = tid & 31;
    const int yi = (tid >> 5) & 1;
    const int Zi = tid >> 6;
    const int w  = ((32 * X0 + xi) << 9) | ((y0 + yi) << 2) | Zi;

    const float4* __restrict__ g4 = (const float4*)(gt + (size_t)w * 32);
    float g[32];
    #pragma unroll
    for (int q = 0; q < 8; ++q) {
        const float4 v = g4[q];
        g[4 * q + 0] = v.x; g[4 * q + 1] = v.y;
        g[4 * q + 2] = v.z; g[4 * q + 3] = v.w;
    }

    float acc = 0.0f;
    #pragma unroll
    for (int b = 0; b < 2; ++b) {
        const unsigned F = fst[b][(xi << 3) | (yi << 2) | Zi];
        unsigned L = 0;
        #pragma unroll
        for (int zz = 0; zz < 32; ++zz) {
            L |= ((latw[b][yi][(Zi << 5) + zz] >> xi) & 1u) << zz;
        }
        const int n2 = __popc(F & L);
        const int n1 = __popc(F | L) - n2;
        const int n0 = 32 - n1 - n2;
        acc += 0.6931471806f * (float)n0 + 1.3132616875f * (float)n1 +
               2.1269280110f * (float)n2;
        float s = 0.0f;
        #pragma unroll
        for (int i = 0; i < 32; ++i) {
            s += g[i] * (float)(((F >> i) & 1u) + ((L >> i) & 1u));
        }
        acc -= s;
    }

    // wave reduce (64 lanes) then block reduce, one atomicAdd per block
    #pragma unroll
    for (int off = 32; off > 0; off >>= 1) acc += __shfl_down(acc, off);

    const int wid  = tid >> 6;
    const int lane = tid & 63;
    if (lane == 0) smem[wid] = acc;
    __syncthreads();
    if (tid == 0) {
        const float tot = smem[0] + smem[1] + smem[2] + smem[3];
        atomicAdd(out, tot * scale);
    }
}

extern "C" void kernel_launch(void* const* d_in, const int* in_sizes, int n_in,
                              void* d_out, int out_size, void* d_ws, size_t ws_size,
                              hipStream_t stream) {
    const float* predF = (const float*)d_in[0];
    const float* predL = (const float*)d_in[1];
    const float* srcF  = (const float*)d_in[2];
    const float* tgtF  = (const float*)d_in[3];
    const float* srcL  = (const float*)d_in[4];
    const float* tgtL  = (const float*)d_in[5];
    const float* gt    = (const float*)d_in[6];
    const float* Ainv  = (const float*)d_in[7];
    const float* tinv  = (const float*)d_in[8];

    const int B = in_sizes[0] / NPIX;               // = 2
    unsigned int* flags = (unsigned int*)d_ws;      // 2B bit-volumes, 256 KiB each
    float* outp = (float*)d_out;

    hipMemsetAsync(flags, 0, (size_t)(2 * B) * NWORDS * sizeof(unsigned int), stream);

    dim3 gridBp(NPIX / 256, 2 * B, SPLITK);
    bp_kernel<<<gridBp, 256, 0, stream>>>(predF, predL, srcF, srcL,
                                          tgtF, tgtL, Ainv, tinv, flags, outp);

    const float scale = 1.0f / ((float)NVOX * (float)B);
    loss_kernel<<<256, 256, 0, stream>>>(flags, gt, outp, scale);
}